// Round 1
// baseline (781.794 us; speedup 1.0000x reference)
//
#include <hip/hip_runtime.h>
#include <cstdint>

#define B_IMG   8
#define NCAND   36720
#define PD      85
#define NCLS    80
#define KC      512
#define MAXDET  300
#define NBUCK   2048
#define CANDCAP 2048

typedef unsigned int u32;
typedef unsigned long long u64;

__device__ __forceinline__ float leaky(float x){ return x >= 0.f ? x : 0.01f*x; }

__device__ __forceinline__ u64 shfl_u64(u64 v, int lane){
  int lo = __shfl((int)(u32)(v & 0xFFFFFFFFull), lane, 64);
  int hi = __shfl((int)(u32)(v >> 32), lane, 64);
  return ((u64)(u32)hi << 32) | (u64)(u32)lo;
}

// ---------------- K1: score + cls + histogram ----------------
// One wave per 64 candidates; stage the 64x85 tile through LDS with float4
// loads (candidate rows are 340B-strided -> direct per-lane reads would be
// uncoalesced). Full blocks are 16B-aligned (64*85*4 = 21760 % 16 == 0).
__global__ __launch_bounds__(64) void k_score(const float* __restrict__ preds,
    u32* __restrict__ sbits, int* __restrict__ clsArr, u32* __restrict__ hist){
  __shared__ __align__(16) float tile[64*PD];
  __shared__ u32 lhist[NBUCK];
  const int img  = blockIdx.y;
  const int lane = threadIdx.x;
  const int base = blockIdx.x * 64;
  const int avail = min(64, NCAND - base);
  const float* src = preds + ((long)img*NCAND + base)*PD;
  for (int i = lane; i < NBUCK; i += 64) lhist[i] = 0;
  if (avail == 64){
    const float4* s4 = (const float4*)src;
    float4* t4 = (float4*)tile;
    #pragma unroll 4
    for (int i = lane; i < (64*PD)/4; i += 64) t4[i] = s4[i];
  } else {
    for (int i = lane; i < avail*PD; i += 64) tile[i] = src[i];
  }
  __syncthreads();
  if (lane < avail){
    const float* p = &tile[lane*PD];
    float obj = p[4];
    float best = p[5]*obj; int bc = 0;      // argmax: strict > keeps first max (JAX argmax)
    #pragma unroll 8
    for (int k = 1; k < NCLS; k++){
      float v = p[5+k]*obj;
      if (v > best){ best = v; bc = k; }
    }
    bool valid = (obj > 0.596f) && (best > 0.596f);
    u32 bits = valid ? __float_as_uint(best) : 0u;  // valid scores in (0.596,1) -> bits in [0x3F189376,0x3F800000)
    long gi = (long)img*NCAND + base + lane;
    sbits[gi]  = bits;
    clsArr[gi] = bc;
    if (bits) atomicAdd(&lhist[(bits - 0x3F000000u) >> 12], 1u);   // bucket in [0x189,0x7FF]
  }
  __syncthreads();
  for (int i = lane; i < NBUCK; i += 64){
    u32 c = lhist[i];
    if (c) atomicAdd(&hist[img*NBUCK + i], c);
  }
}

// ---------------- K2: per-image bit-threshold covering top-512 ----------------
__global__ void k_thresh(const u32* __restrict__ hist, u32* __restrict__ thr){
  if (threadIdx.x != 0) return;
  int img = blockIdx.x;
  const u32* h = hist + img*NBUCK;
  u32 acc = 0; u32 t = 0x3F000000u;         // default: gather every valid candidate
  for (int b = NBUCK-1; b >= 0; b--){
    acc += h[b];
    if (acc >= KC){ t = 0x3F000000u + ((u32)b << 12); break; }
  }
  thr[img] = t;
}

// ---------------- K3: gather candidates >= threshold as sortable keys ----------------
// key = (score_bits << 32) | (0xFFFFFFFF - idx): descending sort == JAX top_k
// order (value desc, index asc on ties).
__global__ __launch_bounds__(256) void k_gather(const u32* __restrict__ sbits,
    const u32* __restrict__ thr, u32* __restrict__ cnt, u64* __restrict__ cand){
  int img = blockIdx.y;
  int n = blockIdx.x*256 + threadIdx.x;
  if (n >= NCAND) return;
  u32 bits = sbits[(long)img*NCAND + n];
  if (bits && bits >= thr[img]){
    u32 pos = atomicAdd(&cnt[img], 1u);
    if (pos < CANDCAP)
      cand[(long)img*CANDCAP + pos] = ((u64)bits << 32) | (u64)(0xFFFFFFFFu - (u32)n);
  }
}

// ---------------- K4: sort -> exact top-512 -> NMS -> stable top-300 ----------------
__global__ __launch_bounds__(512) void k_nms(const float* __restrict__ preds,
    const int* __restrict__ clsArr, const u64* __restrict__ cand,
    const u32* __restrict__ cnt, float* __restrict__ selbox, u32* __restrict__ selcnt){
#pragma clang fp contract(off)
  __shared__ u64 keys[CANDCAP];
  __shared__ float bx1[KC], by1[KC], bx2[KC], by2[KC];   // class-offset boxes
  __shared__ float ox1[KC], oy1[KC], ox2[KC], oy2[KC];   // original boxes
  __shared__ u64 rows[KC][8];
  __shared__ u64 keepw[8];
  const int img = blockIdx.x;
  const int tid = threadIdx.x;
  const int M = min((int)cnt[img], CANDCAP);
  for (int i = tid; i < CANDCAP; i += 512)
    keys[i] = (i < M) ? cand[(long)img*CANDCAP + i] : 0ull;
  if (tid < 8) keepw[tid] = 0ull;
  __syncthreads();
  // bitonic sort, descending
  for (int k = 2; k <= CANDCAP; k <<= 1){
    for (int j = k >> 1; j > 0; j >>= 1){
      for (int p = tid; p < CANDCAP/2; p += 512){
        int i = ((p & ~(j-1)) << 1) | (p & (j-1));
        int l = i | j;
        u64 a = keys[i], b = keys[l];
        bool desc = ((i & k) == 0);
        if (desc ? (a < b) : (a > b)){ keys[i] = b; keys[l] = a; }
      }
      __syncthreads();
    }
  }
  // decode top-512, build boxes, init keep (= score>0)
  {
    u64 key = keys[tid];
    bool pos = (key >> 32) != 0ull;
    if (pos){
      u32 idxn = 0xFFFFFFFFu - (u32)(key & 0xFFFFFFFFull);
      const float* p = preds + ((long)img*NCAND + idxn)*PD;
      float cx = p[0], cy = p[1], w = p[2], h = p[3];
      float hw = w*0.5f, hh = h*0.5f;               // wh/2: exact
      float X1 = cx-hw, Y1 = cy-hh, X2 = cx+hw, Y2 = cy+hh;
      float off = (float)clsArr[(long)img*NCAND + idxn] * 4096.0f;  // exact
      ox1[tid]=X1; oy1[tid]=Y1; ox2[tid]=X2; oy2[tid]=Y2;
      bx1[tid]=X1+off; by1[tid]=Y1+off; bx2[tid]=X2+off; by2[tid]=Y2+off;
      atomicOr(&keepw[tid>>6], 1ull << (tid & 63));
    } else {
      ox1[tid]=0.f; oy1[tid]=0.f; ox2[tid]=0.f; oy2[tid]=0.f;
      bx1[tid]=-4e8f; by1[tid]=-4e8f; bx2[tid]=-4e8f; by2[tid]=-4e8f; // zero-area, iou==0
    }
  }
  __syncthreads();
  // suppression bit-matrix: rows[i] bit j set iff j>i && iou(i,j)>0.45
  {
    const int i = tid;
    float ax1=bx1[i], ay1=by1[i], ax2=bx2[i], ay2=by2[i];
    float areai = (ax2-ax1)*(ay2-ay1);
    for (int w = 0; w < 8; w++){
      u64 bits = 0ull;
      int jbase = w*64;
      for (int b = 0; b < 64; b++){
        int j = jbase + b;
        if (j > i){
          float jx1=bx1[j], jy1=by1[j], jx2=bx2[j], jy2=by2[j];
          float areaj = (jx2-jx1)*(jy2-jy1);
          float ltx = fmaxf(ax1,jx1), lty = fmaxf(ay1,jy1);
          float rbx = fminf(ax2,jx2), rby = fminf(ay2,jy2);
          float ww = fmaxf(rbx-ltx, 0.f);
          float hh = fmaxf(rby-lty, 0.f);
          float inter = ww*hh;
          float iou = inter / (areai + areaj - inter + 1e-7f);  // exact ref op order
          if (iou > 0.45f) bits |= (1ull << b);
        }
      }
      rows[i][w] = bits;
    }
  }
  __syncthreads();
  // greedy pass: wave 0, lanes 0..7 own keep words
  if (tid < 64){
    u64 kw = (tid < 8) ? keepw[tid] : 0ull;
    for (int i = 0; i < KC; i++){
      u64 cw = shfl_u64(kw, i >> 6);
      if ((cw >> (i & 63)) & 1ull){
        if (tid < 8) kw &= ~rows[i][tid];
      }
    }
    if (tid < 8) keepw[tid] = kw;
  }
  __syncthreads();
  // stable compaction of kept boxes (scores already desc => == top_k(sc2,300))
  {
    const int i = tid;
    const int wi = i >> 6, bi = i & 63;
    u64 myw = keepw[wi];
    bool kept = (myw >> bi) & 1ull;
    int rank = 0;
    for (int w = 0; w < wi; w++) rank += __popcll(keepw[w]);
    u64 below = bi ? (myw & ((1ull << bi) - 1ull)) : 0ull;
    rank += __popcll(below);
    if (kept && rank < MAXDET){
      float* sb = selbox + ((long)img*MAXDET + rank)*4;
      sb[0]=ox1[i]; sb[1]=oy1[i]; sb[2]=ox2[i]; sb[3]=oy2[i];
    }
    if (tid == 0){
      int tot = 0;
      for (int w = 0; w < 8; w++) tot += __popcll(keepw[w]);
      selcnt[img] = (u32)min(tot, MAXDET);
    }
  }
}

// ---------------- K5: ROI-align 1x1 (4-pt bilinear mean), 4 levels -> F[1920] ----------------
__global__ __launch_bounds__(256) void k_feat(const float* __restrict__ f1,
    const float* __restrict__ f2, const float* __restrict__ f3, const float* __restrict__ f4,
    const float* __restrict__ selbox, const u32* __restrict__ selcnt, float* __restrict__ F){
  const int img = blockIdx.y, slot = blockIdx.x;
  if (slot >= (int)selcnt[img]) return;
  const float* sb = selbox + ((long)img*MAXDET + slot)*4;
  float x1 = sb[0], y1 = sb[1], x2 = sb[2], y2 = sb[3];
  float* Fo = F + ((long)img*MAXDET + slot)*1920;
  for (int c = threadIdx.x; c < 1920; c += 256){
    const float* f; int H, W, C, cl; float scale;
    if (c < 128)      { f=f1; cl=c;     H=96; W=96; C=128;  scale=0.125f;    }
    else if (c < 384) { f=f2; cl=c-128; H=48; W=48; C=256;  scale=0.0625f;   }
    else if (c < 896) { f=f3; cl=c-384; H=24; W=24; C=512;  scale=0.03125f;  }
    else              { f=f4; cl=c-896; H=12; W=12; C=1024; scale=0.015625f; }
    const float* feat = f + ((long)img*C + cl)*(long)(H*W);
    float bx1=x1*scale, by1=y1*scale, bx2=x2*scale, by2=y2*scale;
    float rw = fmaxf(bx2-bx1, 1.f), rh = fmaxf(by2-by1, 1.f);
    float ys[2] = { by1 + rh*0.25f, by1 + rh*0.75f };
    float xs[2] = { bx1 + rw*0.25f, bx1 + rw*0.75f };
    float acc = 0.f;
    #pragma unroll
    for (int pt = 0; pt < 4; pt++){
      float y = ys[pt>>1], x = xs[pt&1];
      bool valid = (y > -1.f) && (y < (float)H) && (x > -1.f) && (x < (float)W);
      float v = 0.f;
      if (valid){
        float yc = fmaxf(y, 0.f), xc = fmaxf(x, 0.f);
        int y0  = (int)fminf(floorf(yc), (float)(H-1));
        int x0  = (int)fminf(floorf(xc), (float)(W-1));
        int y1i = min(y0+1, H-1), x1i = min(x0+1, W-1);
        float ly = yc - (float)y0, lx = xc - (float)x0;
        float hy = 1.f - ly, hx = 1.f - lx;
        float f00 = feat[y0*W+x0],  f01 = feat[y0*W+x1i];
        float f10 = feat[y1i*W+x0], f11 = feat[y1i*W+x1i];
        v = hy*hx*f00 + hy*lx*f01 + ly*hx*f10 + ly*lx*f11;
      }
      acc += v;
    }
    Fo[c] = acc * 0.25f;
  }
}

// ---------------- K6: MLP 1920->64->64 + output assembly ----------------
// 4 slots per wave: W1 row loaded once per 4 boxes; F reads are wave-uniform
// (scalar). Writes ALL 8x300x68 outputs (zeros for masked rows).
__global__ __launch_bounds__(256) void k_mlp(const float* __restrict__ F,
    const float* __restrict__ selbox, const u32* __restrict__ selcnt,
    const float* __restrict__ W1, const float* __restrict__ b1,
    const float* __restrict__ W2, const float* __restrict__ b2,
    float* __restrict__ out){
  __shared__ float h1[16][64];
  const int img = blockIdx.y;
  const int wv  = threadIdx.x >> 6;
  const int j   = threadIdx.x & 63;
  const int sbase = blockIdx.x*16 + wv*4;
  const int cntv = (int)selcnt[img];
  const float* Fi = F + (long)img*MAXDET*1920;
  const float* Fp0 = Fi + (long)min(sbase+0, MAXDET-1)*1920;
  const float* Fp1 = Fi + (long)min(sbase+1, MAXDET-1)*1920;
  const float* Fp2 = Fi + (long)min(sbase+2, MAXDET-1)*1920;
  const float* Fp3 = Fi + (long)min(sbase+3, MAXDET-1)*1920;
  float a0=0.f, a1=0.f, a2=0.f, a3=0.f;
  #pragma unroll 4
  for (int c = 0; c < 1920; c++){
    float w1v = W1[c*64 + j];
    a0 += Fp0[c]*w1v; a1 += Fp1[c]*w1v; a2 += Fp2[c]*w1v; a3 += Fp3[c]*w1v;
  }
  h1[wv*4+0][j] = leaky(a0 + b1[j]);
  h1[wv*4+1][j] = leaky(a1 + b1[j]);
  h1[wv*4+2][j] = leaky(a2 + b1[j]);
  h1[wv*4+3][j] = leaky(a3 + b1[j]);
  __syncthreads();
  float c0=0.f, c1=0.f, c2=0.f, c3=0.f;
  #pragma unroll 8
  for (int k = 0; k < 64; k++){
    float w2v = W2[k*64 + j];
    c0 += h1[wv*4+0][k]*w2v; c1 += h1[wv*4+1][k]*w2v;
    c2 += h1[wv*4+2][k]*w2v; c3 += h1[wv*4+3][k]*w2v;
  }
  float hv[4] = { leaky(c0+b2[j]), leaky(c1+b2[j]), leaky(c2+b2[j]), leaky(c3+b2[j]) };
  #pragma unroll
  for (int s = 0; s < 4; s++){
    int slot = sbase + s;
    if (slot >= MAXDET) continue;
    float* o = out + ((long)img*MAXDET + slot)*68;
    if (slot < cntv){
      o[4+j] = hv[s];
      if (j < 4) o[j] = selbox[((long)img*MAXDET + slot)*4 + j] / 768.0f;
    } else {
      o[4+j] = 0.f;
      if (j < 4) o[j] = 0.f;
    }
  }
}

// ---------------- workspace layout (bytes) ----------------
// 0        hist   u32[8][2048]   65536
// 65536    cnt    u32[8]
// 65792    thr    u32[8]
// 66560    sbits  u32[8][36720]  1175040
// 1241600  cls    i32[8][36720]  1175040
// 2416640  cand   u64[8][2048]   131072
// 2547712  selbox f32[8][300][4] 38400
// 2586112  selcnt u32[8]
// 2586368  F      f32[8][300][1920] 18432000  -> total ~21.0 MB

extern "C" void kernel_launch(void* const* d_in, const int* in_sizes, int n_in,
                              void* d_out, int out_size, void* d_ws, size_t ws_size,
                              hipStream_t stream){
  const float* preds = (const float*)d_in[0];
  const float* f1 = (const float*)d_in[1];
  const float* f2 = (const float*)d_in[2];
  const float* f3 = (const float*)d_in[3];
  const float* f4 = (const float*)d_in[4];
  const float* W1 = (const float*)d_in[5];
  const float* b1 = (const float*)d_in[6];
  const float* W2 = (const float*)d_in[7];
  const float* b2 = (const float*)d_in[8];
  float* out = (float*)d_out;
  char* ws = (char*)d_ws;
  u32* hist  = (u32*)(ws + 0);
  u32* cnt   = (u32*)(ws + 65536);
  u32* thr   = (u32*)(ws + 65792);
  u32* sbits = (u32*)(ws + 66560);
  int* clsA  = (int*)(ws + 1241600);
  u64* cand  = (u64*)(ws + 2416640);
  float* selb= (float*)(ws + 2547712);
  u32* selc  = (u32*)(ws + 2586112);
  float* F   = (float*)(ws + 2586368);

  hipMemsetAsync(ws, 0, 66560, stream);   // zero hist + cnt (+thr)

  dim3 g1((NCAND+63)/64, B_IMG);
  k_score<<<g1, 64, 0, stream>>>(preds, sbits, clsA, hist);
  k_thresh<<<B_IMG, 64, 0, stream>>>(hist, thr);
  dim3 g3((NCAND+255)/256, B_IMG);
  k_gather<<<g3, 256, 0, stream>>>(sbits, thr, cnt, cand);
  k_nms<<<B_IMG, 512, 0, stream>>>(preds, clsA, cand, cnt, selb, selc);
  dim3 g5(MAXDET, B_IMG);
  k_feat<<<g5, 256, 0, stream>>>(f1, f2, f3, f4, selb, selc, F);
  dim3 g6((MAXDET+15)/16, B_IMG);
  k_mlp<<<g6, 256, 0, stream>>>(F, selb, selc, W1, b1, W2, b2, out);
}

// Round 2
// 599.471 us; speedup vs baseline: 1.3041x; 1.3041x over previous
//
#include <hip/hip_runtime.h>
#include <cstdint>

#define B_IMG   8
#define NCAND   36720
#define PD      85
#define NCLS    80
#define KC      512
#define MAXDET  300
#define NBUCK   2048
#define CANDCAP 2048

typedef unsigned int u32;
typedef unsigned long long u64;

__device__ __forceinline__ float leaky(float x){ return x >= 0.f ? x : 0.01f*x; }

__device__ __forceinline__ u64 shfl_u64(u64 v, int lane){
  int lo = __shfl((int)(u32)(v & 0xFFFFFFFFull), lane, 64);
  int hi = __shfl((int)(u32)(v >> 32), lane, 64);
  return ((u64)(u32)hi << 32) | (u64)(u32)lo;
}

// ---------------- K1: score + cls + direct-atomic histogram ----------------
// One wave per 64 candidates; stage the 64x85 tile through LDS with float4
// loads (candidate rows are 340B-strided -> direct per-lane reads would be
// uncoalesced). Valid candidates (~40%) atomicAdd the global histogram
// directly (~116k atomics total) -- cheaper than per-block 2048-bucket
// LDS init+merge.
__global__ __launch_bounds__(64) void k_score(const float* __restrict__ preds,
    u32* __restrict__ sbits, int* __restrict__ clsArr, u32* __restrict__ hist){
  __shared__ __align__(16) float tile[64*PD];
  const int img  = blockIdx.y;
  const int lane = threadIdx.x;
  const int base = blockIdx.x * 64;
  const int avail = min(64, NCAND - base);
  const float* src = preds + ((long)img*NCAND + base)*PD;
  if (avail == 64){
    const float4* s4 = (const float4*)src;
    float4* t4 = (float4*)tile;
    #pragma unroll 4
    for (int i = lane; i < (64*PD)/4; i += 64) t4[i] = s4[i];
  } else {
    for (int i = lane; i < avail*PD; i += 64) tile[i] = src[i];
  }
  __syncthreads();
  if (lane < avail){
    const float* p = &tile[lane*PD];
    float obj = p[4];
    float best = p[5]*obj; int bc = 0;      // argmax: strict > keeps first max (JAX argmax)
    #pragma unroll 8
    for (int k = 1; k < NCLS; k++){
      float v = p[5+k]*obj;
      if (v > best){ best = v; bc = k; }
    }
    bool valid = (obj > 0.596f) && (best > 0.596f);
    u32 bits = valid ? __float_as_uint(best) : 0u;  // valid scores in (0.596,1) -> bits in [0x3F189376,0x3F800000)
    long gi = (long)img*NCAND + base + lane;
    sbits[gi]  = bits;
    clsArr[gi] = bc;
    if (bits) atomicAdd(&hist[img*NBUCK + ((bits - 0x3F000000u) >> 12)], 1u);
  }
}

// ---------------- K2: per-image bit-threshold covering top-512 ----------------
// One wave per image: per-group suffix-scan + ballot to find the highest
// bucket b with count(>=b) >= 512.
__global__ __launch_bounds__(64) void k_thresh(const u32* __restrict__ hist,
                                               u32* __restrict__ thr){
  const int img = blockIdx.x;
  const int lane = threadIdx.x;
  const u32* h = hist + img*NBUCK;
  u32 acc = 0; u32 result = 0x3F000000u; bool found = false;
  for (int g = NBUCK/64 - 1; g >= 0 && !found; g--){
    u32 v = h[g*64 + lane];
    u32 s = v;                                   // suffix sum over lanes >= lane
    #pragma unroll
    for (int off = 1; off < 64; off <<= 1){
      u32 t = __shfl_down(s, off, 64);
      s += (lane + off < 64) ? t : 0u;
    }
    u64 mask = __ballot(acc + s >= KC);          // count at-or-above this bucket
    if (mask){
      int hl = 63 - __clzll(mask);               // highest satisfying bucket
      result = 0x3F000000u + ((u32)(g*64 + hl) << 12);
      found = true;                              // wave-uniform
    }
    acc += __shfl(s, 0, 64);                     // group total
  }
  if (lane == 0) thr[img] = result;
}

// ---------------- K3: gather candidates >= threshold as sortable keys ----------------
// key = (score_bits << 32) | (0xFFFFFFFF - idx): descending sort == JAX top_k
// order (value desc, index asc on ties).
__global__ __launch_bounds__(256) void k_gather(const u32* __restrict__ sbits,
    const u32* __restrict__ thr, u32* __restrict__ cnt, u64* __restrict__ cand){
  int img = blockIdx.y;
  int n = blockIdx.x*256 + threadIdx.x;
  if (n >= NCAND) return;
  u32 bits = sbits[(long)img*NCAND + n];
  if (bits && bits >= thr[img]){
    u32 pos = atomicAdd(&cnt[img], 1u);
    if (pos < CANDCAP)
      cand[(long)img*CANDCAP + pos] = ((u64)bits << 32) | (u64)(0xFFFFFFFFu - (u32)n);
  }
}

// ---------------- K4: sort -> exact top-512 -> NMS -> stable top-300 ----------------
__global__ __launch_bounds__(512) void k_nms(const float* __restrict__ preds,
    const int* __restrict__ clsArr, const u64* __restrict__ cand,
    const u32* __restrict__ cnt, float* __restrict__ selbox, u32* __restrict__ selcnt){
#pragma clang fp contract(off)
  __shared__ u64 keys[CANDCAP];
  __shared__ float bx1[KC], by1[KC], bx2[KC], by2[KC];   // class-offset boxes
  __shared__ float ox1[KC], oy1[KC], ox2[KC], oy2[KC];   // original boxes
  __shared__ u64 rows[KC][8];
  __shared__ u64 keepw[8];
  const int img = blockIdx.x;
  const int tid = threadIdx.x;
  const int M = min((int)cnt[img], CANDCAP);
  for (int i = tid; i < CANDCAP; i += 512)
    keys[i] = (i < M) ? cand[(long)img*CANDCAP + i] : 0ull;
  if (tid < 8) keepw[tid] = 0ull;
  __syncthreads();
  // bitonic sort, descending
  for (int k = 2; k <= CANDCAP; k <<= 1){
    for (int j = k >> 1; j > 0; j >>= 1){
      for (int p = tid; p < CANDCAP/2; p += 512){
        int i = ((p & ~(j-1)) << 1) | (p & (j-1));
        int l = i | j;
        u64 a = keys[i], b = keys[l];
        bool desc = ((i & k) == 0);
        if (desc ? (a < b) : (a > b)){ keys[i] = b; keys[l] = a; }
      }
      __syncthreads();
    }
  }
  // decode top-512, build boxes, init keep (= score>0)
  {
    u64 key = keys[tid];
    bool pos = (key >> 32) != 0ull;
    if (pos){
      u32 idxn = 0xFFFFFFFFu - (u32)(key & 0xFFFFFFFFull);
      const float* p = preds + ((long)img*NCAND + idxn)*PD;
      float cx = p[0], cy = p[1], w = p[2], h = p[3];
      float hw = w*0.5f, hh = h*0.5f;               // wh/2: exact
      float X1 = cx-hw, Y1 = cy-hh, X2 = cx+hw, Y2 = cy+hh;
      float off = (float)clsArr[(long)img*NCAND + idxn] * 4096.0f;  // exact
      ox1[tid]=X1; oy1[tid]=Y1; ox2[tid]=X2; oy2[tid]=Y2;
      bx1[tid]=X1+off; by1[tid]=Y1+off; bx2[tid]=X2+off; by2[tid]=Y2+off;
      atomicOr(&keepw[tid>>6], 1ull << (tid & 63));
    } else {
      ox1[tid]=0.f; oy1[tid]=0.f; ox2[tid]=0.f; oy2[tid]=0.f;
      bx1[tid]=-4e8f; by1[tid]=-4e8f; bx2[tid]=-4e8f; by2[tid]=-4e8f; // zero-area, iou==0
    }
  }
  __syncthreads();
  // suppression bit-matrix: rows[i] bit j set iff j>i && iou(i,j)>0.45
  {
    const int i = tid;
    float ax1=bx1[i], ay1=by1[i], ax2=bx2[i], ay2=by2[i];
    float areai = (ax2-ax1)*(ay2-ay1);
    for (int w = 0; w < 8; w++){
      u64 bits = 0ull;
      int jbase = w*64;
      for (int b = 0; b < 64; b++){
        int j = jbase + b;
        if (j > i){
          float jx1=bx1[j], jy1=by1[j], jx2=bx2[j], jy2=by2[j];
          float areaj = (jx2-jx1)*(jy2-jy1);
          float ltx = fmaxf(ax1,jx1), lty = fmaxf(ay1,jy1);
          float rbx = fminf(ax2,jx2), rby = fminf(ay2,jy2);
          float ww = fmaxf(rbx-ltx, 0.f);
          float hh = fmaxf(rby-lty, 0.f);
          float inter = ww*hh;
          float iou = inter / (areai + areaj - inter + 1e-7f);  // exact ref op order
          if (iou > 0.45f) bits |= (1ull << b);
        }
      }
      rows[i][w] = bits;
    }
  }
  __syncthreads();
  // greedy pass: wave 0, lanes 0..7 own keep words
  if (tid < 64){
    u64 kw = (tid < 8) ? keepw[tid] : 0ull;
    for (int i = 0; i < KC; i++){
      u64 cw = shfl_u64(kw, i >> 6);
      if ((cw >> (i & 63)) & 1ull){
        if (tid < 8) kw &= ~rows[i][tid];
      }
    }
    if (tid < 8) keepw[tid] = kw;
  }
  __syncthreads();
  // stable compaction of kept boxes (scores already desc => == top_k(sc2,300))
  {
    const int i = tid;
    const int wi = i >> 6, bi = i & 63;
    u64 myw = keepw[wi];
    bool kept = (myw >> bi) & 1ull;
    int rank = 0;
    for (int w = 0; w < wi; w++) rank += __popcll(keepw[w]);
    u64 below = bi ? (myw & ((1ull << bi) - 1ull)) : 0ull;
    rank += __popcll(below);
    if (kept && rank < MAXDET){
      float* sb = selbox + ((long)img*MAXDET + rank)*4;
      sb[0]=ox1[i]; sb[1]=oy1[i]; sb[2]=ox2[i]; sb[3]=oy2[i];
    }
    if (tid == 0){
      int tot = 0;
      for (int w = 0; w < 8; w++) tot += __popcll(keepw[w]);
      selcnt[img] = (u32)min(tot, MAXDET);
    }
  }
}

// ---------------- K5: ROI-align 1x1 (4-pt bilinear mean), 4 levels -> F[1920] ----------------
__global__ __launch_bounds__(256) void k_feat(const float* __restrict__ f1,
    const float* __restrict__ f2, const float* __restrict__ f3, const float* __restrict__ f4,
    const float* __restrict__ selbox, const u32* __restrict__ selcnt, float* __restrict__ F){
  const int img = blockIdx.y, slot = blockIdx.x;
  if (slot >= (int)selcnt[img]) return;
  const float* sb = selbox + ((long)img*MAXDET + slot)*4;
  float x1 = sb[0], y1 = sb[1], x2 = sb[2], y2 = sb[3];
  float* Fo = F + ((long)img*MAXDET + slot)*1920;
  for (int c = threadIdx.x; c < 1920; c += 256){
    const float* f; int H, W, C, cl; float scale;
    if (c < 128)      { f=f1; cl=c;     H=96; W=96; C=128;  scale=0.125f;    }
    else if (c < 384) { f=f2; cl=c-128; H=48; W=48; C=256;  scale=0.0625f;   }
    else if (c < 896) { f=f3; cl=c-384; H=24; W=24; C=512;  scale=0.03125f;  }
    else              { f=f4; cl=c-896; H=12; W=12; C=1024; scale=0.015625f; }
    const float* feat = f + ((long)img*C + cl)*(long)(H*W);
    float bx1=x1*scale, by1=y1*scale, bx2=x2*scale, by2=y2*scale;
    float rw = fmaxf(bx2-bx1, 1.f), rh = fmaxf(by2-by1, 1.f);
    float ys[2] = { by1 + rh*0.25f, by1 + rh*0.75f };
    float xs[2] = { bx1 + rw*0.25f, bx1 + rw*0.75f };
    float acc = 0.f;
    #pragma unroll
    for (int pt = 0; pt < 4; pt++){
      float y = ys[pt>>1], x = xs[pt&1];
      bool valid = (y > -1.f) && (y < (float)H) && (x > -1.f) && (x < (float)W);
      float v = 0.f;
      if (valid){
        float yc = fmaxf(y, 0.f), xc = fmaxf(x, 0.f);
        int y0  = (int)fminf(floorf(yc), (float)(H-1));
        int x0  = (int)fminf(floorf(xc), (float)(W-1));
        int y1i = min(y0+1, H-1), x1i = min(x0+1, W-1);
        float ly = yc - (float)y0, lx = xc - (float)x0;
        float hy = 1.f - ly, hx = 1.f - lx;
        float f00 = feat[y0*W+x0],  f01 = feat[y0*W+x1i];
        float f10 = feat[y1i*W+x0], f11 = feat[y1i*W+x1i];
        v = hy*hx*f00 + hy*lx*f01 + ly*hx*f10 + ly*lx*f11;
      }
      acc += v;
    }
    Fo[c] = acc * 0.25f;
  }
}

// ---------------- K6a: layer-1 GEMM, K-split x6, atomic accumulate ----------------
// M=300x8 slots, N=64, K=1920 split into 6x320. 8 slots/wave, 1920 waves
// (~7.5/CU): 8 independent FMA chains + unroll-4 = deep outstanding-load
// queue. W1 row load is fully coalesced (256B/wave); F loads are same-address
// broadcasts (L1/L2 hits).
__global__ __launch_bounds__(256) void k_mlp1(const float* __restrict__ F,
    const float* __restrict__ W1, float* __restrict__ h1acc){
  const int img = blockIdx.z;
  const int k0 = blockIdx.y * 320;
  const int wv = threadIdx.x >> 6;
  const int j  = threadIdx.x & 63;
  const int sbase = blockIdx.x*32 + wv*8;
  const float* Fi = F + (long)img*MAXDET*1920;
  const float* Fp[8];
  #pragma unroll
  for (int s = 0; s < 8; s++)
    Fp[s] = Fi + (long)min(sbase+s, MAXDET-1)*1920 + k0;
  const float* Wp = W1 + (long)k0*64 + j;
  float a[8] = {0,0,0,0,0,0,0,0};
  #pragma unroll 4
  for (int c = 0; c < 320; c++){
    float w1v = Wp[(long)c*64];
    #pragma unroll
    for (int s = 0; s < 8; s++) a[s] += Fp[s][c] * w1v;
  }
  float* hb = h1acc + ((long)img*304 + sbase)*64 + j;
  #pragma unroll
  for (int s = 0; s < 8; s++){
    if (sbase + s < MAXDET) atomicAdd(hb + (long)s*64, a[s]);
  }
}

// ---------------- K6b: bias+leaky, layer-2 via shfl broadcast, assembly ----------------
__global__ __launch_bounds__(256) void k_mlp2(const float* __restrict__ h1acc,
    const float* __restrict__ selbox, const u32* __restrict__ selcnt,
    const float* __restrict__ b1, const float* __restrict__ W2,
    const float* __restrict__ b2, float* __restrict__ out){
  const int img = blockIdx.y;
  const int wv = threadIdx.x >> 6;
  const int j  = threadIdx.x & 63;
  const int slot = blockIdx.x*4 + wv;
  if (slot >= MAXDET) return;
  const int cntv = (int)selcnt[img];
  float* o = out + ((long)img*MAXDET + slot)*68;
  if (slot >= cntv){
    o[4+j] = 0.f;
    if (j < 4) o[j] = 0.f;
    return;
  }
  float hj = leaky(h1acc[((long)img*304 + slot)*64 + j] + b1[j]);
  float c = 0.f;
  #pragma unroll 8
  for (int k = 0; k < 64; k++){
    float hk = __shfl(hj, k, 64);
    c += hk * W2[k*64 + j];
  }
  o[4+j] = leaky(c + b2[j]);
  if (j < 4) o[j] = selbox[((long)img*MAXDET + slot)*4 + j] / 768.0f;
}

// ---------------- workspace layout (bytes) ----------------
// 0        hist   u32[8][2048]   65536
// 65536    cnt    u32[8]
// 65792    thr    u32[8]
// 66560    sbits  u32[8][36720]  1175040   } h1acc f32[8][304][64] (622592)
//                                          } overlaps sbits after k_gather
// 1241600  cls    i32[8][36720]  1175040
// 2416640  cand   u64[8][2048]   131072
// 2547712  selbox f32[8][300][4] 38400
// 2586112  selcnt u32[8]
// 2586368  F      f32[8][300][1920] 18432000  -> total ~21.0 MB

extern "C" void kernel_launch(void* const* d_in, const int* in_sizes, int n_in,
                              void* d_out, int out_size, void* d_ws, size_t ws_size,
                              hipStream_t stream){
  const float* preds = (const float*)d_in[0];
  const float* f1 = (const float*)d_in[1];
  const float* f2 = (const float*)d_in[2];
  const float* f3 = (const float*)d_in[3];
  const float* f4 = (const float*)d_in[4];
  const float* W1 = (const float*)d_in[5];
  const float* b1 = (const float*)d_in[6];
  const float* W2 = (const float*)d_in[7];
  const float* b2 = (const float*)d_in[8];
  float* out = (float*)d_out;
  char* ws = (char*)d_ws;
  u32* hist  = (u32*)(ws + 0);
  u32* cnt   = (u32*)(ws + 65536);
  u32* thr   = (u32*)(ws + 65792);
  u32* sbits = (u32*)(ws + 66560);
  float* h1acc = (float*)(ws + 66560);   // reuses sbits after k_gather
  int* clsA  = (int*)(ws + 1241600);
  u64* cand  = (u64*)(ws + 2416640);
  float* selb= (float*)(ws + 2547712);
  u32* selc  = (u32*)(ws + 2586112);
  float* F   = (float*)(ws + 2586368);

  hipMemsetAsync(ws, 0, 66560, stream);   // zero hist + cnt (+thr)

  dim3 g1((NCAND+63)/64, B_IMG);
  k_score<<<g1, 64, 0, stream>>>(preds, sbits, clsA, hist);
  k_thresh<<<B_IMG, 64, 0, stream>>>(hist, thr);
  dim3 g3((NCAND+255)/256, B_IMG);
  k_gather<<<g3, 256, 0, stream>>>(sbits, thr, cnt, cand);
  hipMemsetAsync(h1acc, 0, (size_t)8*304*64*4, stream);  // sbits dead now
  k_nms<<<B_IMG, 512, 0, stream>>>(preds, clsA, cand, cnt, selb, selc);
  dim3 g5(MAXDET, B_IMG);
  k_feat<<<g5, 256, 0, stream>>>(f1, f2, f3, f4, selb, selc, F);
  dim3 g6a(10, 6, B_IMG);
  k_mlp1<<<g6a, 256, 0, stream>>>(F, W1, h1acc);
  dim3 g6b((MAXDET+3)/4, B_IMG);
  k_mlp2<<<g6b, 256, 0, stream>>>(h1acc, selb, selc, b1, W2, b2, out);
}